// Round 3
// baseline (120.470 us; speedup 1.0000x reference)
//
#include <hip/hip_runtime.h>
#include <stdint.h>

typedef short bf16x8 __attribute__((ext_vector_type(8)));
typedef float f32x4 __attribute__((ext_vector_type(4)));

__device__ __forceinline__ unsigned short f2bf(float f) {
  unsigned u = __float_as_uint(f);
  u += 0x7fffu + ((u >> 16) & 1u);   // RNE round to bf16
  return (unsigned short)(u >> 16);
}

// ---------------- prep: emb fp32 -> bf16 (ws), half ||e||^2 ----------------
__global__ __launch_bounds__(256) void k_prep(const float* __restrict__ emb,
                                              unsigned short* __restrict__ embb,
                                              float* __restrict__ h2) {
  const int t = threadIdx.x;
  const int n = blockIdx.x * 8 + (t >> 5);
  const int c0 = (t & 31) * 8;
  const float* src = emb + (size_t)n * 256 + c0;
  float s = 0.f;
  union { bf16x8 v; unsigned short u[8]; } pk;
#pragma unroll
  for (int i = 0; i < 8; ++i) {
    float f = src[i];
    s += f * f;
    pk.u[i] = f2bf(f);
  }
  *(bf16x8*)(embb + (size_t)n * 256 + c0) = pk.v;
#pragma unroll
  for (int m = 1; m < 32; m <<= 1) s += __shfl_xor(s, m);
  if ((t & 31) == 0) h2[n] = 0.5f * s;
}

// ---------------- prez: z [B,C,H,W] fp32 -> zb [row=(b,hw)][c] bf16 + sum z^2
__global__ __launch_bounds__(256) void k_prez(const float* __restrict__ z,
                                              unsigned short* __restrict__ zb,
                                              float* __restrict__ acc) {
  __shared__ unsigned int lds[64 * 128];   // [hw][cpair ^ (hw&31)]
  __shared__ float rsum[4];
  const int t = threadIdx.x;
  const int b = blockIdx.x >> 4, hwg = blockIdx.x & 15;
  const int hw = t & 63, cq = t >> 6;
  const float* zp = z + (size_t)b * 262144 + hwg * 64 + hw;
  float ss = 0.f;
#pragma unroll
  for (int i = 0; i < 32; ++i) {
    const int c0 = cq * 64 + 2 * i;
    const float f0 = zp[(size_t)c0 * 1024];
    const float f1 = zp[(size_t)(c0 + 1) * 1024];
    ss += f0 * f0 + f1 * f1;
    const unsigned u = ((unsigned)f2bf(f1) << 16) | (unsigned)f2bf(f0);
    const int cp = cq * 32 + i;
    lds[hw * 128 + (cp ^ (hw & 31))] = u;
  }
#pragma unroll
  for (int m = 1; m < 64; m <<= 1) ss += __shfl_xor(ss, m);
  if ((t & 63) == 0) rsum[t >> 6] = ss;
  __syncthreads();
  if (t == 0) atomicAdd(acc, rsum[0] + rsum[1] + rsum[2] + rsum[3]);
  unsigned int* zbd = (unsigned int*)zb;
  const size_t tb = ((size_t)b * 1024 + hwg * 64) * 128;   // dword index
#pragma unroll
  for (int s = 0; s < 8; ++s) {
    const int r = s * 8 + (t >> 5);
    const int d0 = (t & 31) * 4;
    uint4 v;
    v.x = lds[r * 128 + ((d0 + 0) ^ (r & 31))];
    v.y = lds[r * 128 + ((d0 + 1) ^ (r & 31))];
    v.z = lds[r * 128 + ((d0 + 2) ^ (r & 31))];
    v.w = lds[r * 128 + ((d0 + 3) ^ (r & 31))];
    *(uint4*)(zbd + tb + (size_t)s * 1024 + (size_t)t * 4) = v;
  }
}

// ---------------- main: B-chunk in registers, A-tiles pipelined ------------
// grid: 512 blocks = 64 rowgroups x 8 chunks. block: 512 rows x 128 emb.
__global__ __launch_bounds__(256, 3) void k_main(
    const unsigned short* __restrict__ zb, const unsigned short* __restrict__ embb,
    const float* __restrict__ h2, float2* __restrict__ pv) {

  __shared__ __align__(16) unsigned short lbuf[3][8192];   // 3 x 16KB tiles

  const int t = threadIdx.x;
  const int lane = t & 63;
  const int w = t >> 6;
  const int l15 = lane & 15;
  const int l4 = lane >> 4;
  const int rg = blockIdx.x >> 3;
  const int ch = blockIdx.x & 7;

  // stage a 32-row x 256-col bf16 tile (16KB): linear LDS dest, swizzle in src addr
  auto stage = [&](const unsigned short* base, int buf) {
#pragma unroll
    for (int rd = 0; rd < 4; ++rd) {
      const int rl = rd * 8 + (t >> 5);
      const int p = t & 31;
      const int kc = p ^ (rl & 7);
      const unsigned short* g = base + (size_t)rl * 256 + kc * 8;
      char* l = (char*)(&lbuf[buf][0]) + rd * 4096 + w * 1024;
      __builtin_amdgcn_global_load_lds((const __attribute__((address_space(1))) void*)g,
                                       (__attribute__((address_space(3))) void*)l,
                                       16, 0, 0);
    }
  };
  const unsigned short* Bbase = embb + (size_t)(ch * 128) * 256;
  const unsigned short* Abase = zb + (size_t)(rg * 512) * 256;

  const float h0 = h2[ch * 128 + w * 32 + l15];
  const float h1 = h2[ch * 128 + w * 32 + 16 + l15];

  // ---- prologue: B chunk (4 pieces of 32 emb) -> registers
  bf16x8 bfr[8][2];   // [kk][ni]
  stage(Bbase + (size_t)0 * 32 * 256, 0);
  stage(Bbase + (size_t)1 * 32 * 256, 1);
  stage(Bbase + (size_t)2 * 32 * 256, 2);
  asm volatile("s_waitcnt vmcnt(0)" ::: "memory");
  __builtin_amdgcn_s_barrier();
  if (w < 3) {
#pragma unroll
    for (int kk = 0; kk < 8; ++kk)
#pragma unroll
      for (int ni = 0; ni < 2; ++ni) {
        const int rl = ni * 16 + l15;
        const int p = (kk * 4 + l4) ^ (rl & 7);
        bfr[kk][ni] = *(const bf16x8*)((const char*)&lbuf[w][0] + rl * 512 + p * 16);
      }
  }
  asm volatile("s_waitcnt lgkmcnt(0)" ::: "memory");
  __builtin_amdgcn_s_barrier();
  stage(Bbase + (size_t)3 * 32 * 256, 0);
  asm volatile("s_waitcnt vmcnt(0)" ::: "memory");
  __builtin_amdgcn_s_barrier();
  if (w == 3) {
#pragma unroll
    for (int kk = 0; kk < 8; ++kk)
#pragma unroll
      for (int ni = 0; ni < 2; ++ni) {
        const int rl = ni * 16 + l15;
        const int p = (kk * 4 + l4) ^ (rl & 7);
        bfr[kk][ni] = *(const bf16x8*)((const char*)&lbuf[0][0] + rl * 512 + p * 16);
      }
  }
  asm volatile("s_waitcnt lgkmcnt(0)" ::: "memory");
  __builtin_amdgcn_s_barrier();

  // ---- A pipeline prologue: tiles 0,1
  stage(Abase + (size_t)0 * 32 * 256, 0);
  stage(Abase + (size_t)1 * 32 * 256, 1);
  asm volatile("s_waitcnt vmcnt(4)" ::: "memory");
  __builtin_amdgcn_s_barrier();

  for (int tl = 0; tl < 16; ++tl) {
    // issue stage for tl+2 (clamped dummy keeps vmcnt arithmetic constant)
    const int s = (tl + 2 < 16) ? (tl + 2) : 15;
    stage(Abase + (size_t)s * 32 * 256, (tl + 2) % 3);

    const char* buf = (const char*)&lbuf[tl % 3][0];
    f32x4 acc[2][2];
#pragma unroll
    for (int mi = 0; mi < 2; ++mi)
#pragma unroll
      for (int ni = 0; ni < 2; ++ni)
#pragma unroll
        for (int q = 0; q < 4; ++q) acc[mi][ni][q] = 0.f;

#pragma unroll
    for (int kk = 0; kk < 8; ++kk) {
      bf16x8 a0, a1;
      {
        const int r0 = l15;
        const int p0 = (kk * 4 + l4) ^ (r0 & 7);
        a0 = *(const bf16x8*)(buf + r0 * 512 + p0 * 16);
        const int r1 = 16 + l15;
        const int p1 = (kk * 4 + l4) ^ (r1 & 7);
        a1 = *(const bf16x8*)(buf + r1 * 512 + p1 * 16);
      }
      acc[0][0] = __builtin_amdgcn_mfma_f32_16x16x32_bf16(a0, bfr[kk][0], acc[0][0], 0, 0, 0);
      acc[0][1] = __builtin_amdgcn_mfma_f32_16x16x32_bf16(a0, bfr[kk][1], acc[0][1], 0, 0, 0);
      acc[1][0] = __builtin_amdgcn_mfma_f32_16x16x32_bf16(a1, bfr[kk][0], acc[1][0], 0, 0, 0);
      acc[1][1] = __builtin_amdgcn_mfma_f32_16x16x32_bf16(a1, bfr[kk][1], acc[1][1], 0, 0, 0);
    }

    // fold argmax over this chunk's 32 cols per lane-row, store per-wave partial
    const int rowbase = rg * 512 + tl * 32;
    const int c0 = ch * 128 + w * 32 + l15;
#pragma unroll
    for (int mi = 0; mi < 2; ++mi)
#pragma unroll
      for (int j = 0; j < 4; ++j) {
        float v = acc[mi][0][j] - h0;
        int ci = c0;
        const float v1 = acc[mi][1][j] - h1;
        if (v1 > v || (v1 == v && c0 + 16 < ci)) { v = v1; ci = c0 + 16; }
#pragma unroll
        for (int m = 1; m < 16; m <<= 1) {
          const float ov = __shfl_xor(v, m);
          const int oi = __shfl_xor(ci, m);
          if (ov > v || (ov == v && oi < ci)) { v = ov; ci = oi; }
        }
        if (l15 == 0) {
          const int row = rowbase + mi * 16 + l4 * 4 + j;
          pv[(size_t)row * 32 + ch * 4 + w] = float2{v, __int_as_float(ci)};
        }
      }

    // counted wait: newest 12 = stage(tl+2)[4] + pv stores[8] -> stage(tl+1) done
    asm volatile("s_waitcnt vmcnt(12)" ::: "memory");
    __builtin_amdgcn_s_barrier();
  }
}

// ---------------- final: merge 32 partials/row, gather, write, loss --------
__global__ __launch_bounds__(256) void k_final(const float2* __restrict__ pv,
                                               const float* __restrict__ emb,
                                               float* __restrict__ out,
                                               float* __restrict__ acc) {
  __shared__ float mv[4][64];
  __shared__ int mi_[4][64];
  __shared__ int sidx[64];
  const int t = threadIdx.x;
  const int b = blockIdx.x >> 4, hwg = blockIdx.x & 15;
  const int rl = t & 63, q = t >> 6;
  const size_t row = (size_t)b * 1024 + hwg * 64 + rl;
  float bv = -1e30f;
  int bi = 1 << 30;
#pragma unroll
  for (int i = 0; i < 8; ++i) {
    const float2 c = pv[row * 32 + q * 8 + i];
    const int ci = __float_as_int(c.y);
    if (c.x > bv || (c.x == bv && ci < bi)) { bv = c.x; bi = ci; }
  }
  mv[q][rl] = bv;
  mi_[q][rl] = bi;
  __syncthreads();
  if (t < 64) {
    float v = mv[0][t];
    int ci = mi_[0][t];
#pragma unroll
    for (int qq = 1; qq < 4; ++qq) {
      const float ov = mv[qq][t];
      const int oi = mi_[qq][t];
      if (ov > v || (ov == v && oi < ci)) { v = ov; ci = oi; }
    }
    sidx[t] = ci;
    float tsum = v;
#pragma unroll
    for (int m = 1; m < 64; m <<= 1) tsum += __shfl_xor(tsum, m);
    if (t == 0) atomicAdd(acc, -2.f * tsum);
  }
  __syncthreads();
  const int ii = sidx[rl];
  const float* ep = emb + (size_t)ii * 256;
  float* op = out + (size_t)b * 262144 + hwg * 64 + rl;
#pragma unroll 8
  for (int i = 0; i < 64; ++i) {
    const int c = i * 4 + q;
    op[(size_t)c * 1024] = ep[c];
  }
}

// ---------------- finalize loss ----------------
__global__ void k_fin(const float* __restrict__ acc_g, float* __restrict__ lossp) {
  if (threadIdx.x == 0) lossp[0] = 1.25f * acc_g[0] * (1.0f / 8388608.0f);
}

extern "C" void kernel_launch(void* const* d_in, const int* in_sizes, int n_in,
                              void* d_out, int out_size, void* d_ws, size_t ws_size,
                              hipStream_t stream) {
  (void)in_sizes; (void)n_in; (void)ws_size;
  const float* z   = (const float*)d_in[0];
  const float* emb = (const float*)d_in[1];
  float* out = (float*)d_out;
  char* ws = (char*)d_ws;
  unsigned short* embb = (unsigned short*)ws;                  // 512 KB
  float* h2  = (float*)(ws + 524288);                          // 4 KB
  float* acc = (float*)(ws + 528384);                          // 16 B
  unsigned short* zb = (unsigned short*)(ws + (1 << 20));      // 16 MB
  float2* pv = (float2*)(ws + (1 << 20) + 16777216);           // 8 MB

  hipMemsetAsync(acc, 0, 4, stream);
  hipLaunchKernelGGL(k_prep, dim3(128), dim3(256), 0, stream, emb, embb, h2);
  hipLaunchKernelGGL(k_prez, dim3(512), dim3(256), 0, stream, z, zb, acc);
  hipLaunchKernelGGL(k_main, dim3(512), dim3(256), 0, stream, zb, embb, h2, pv);
  hipLaunchKernelGGL(k_final, dim3(512), dim3(256), 0, stream, pv, emb, out, acc);
  hipLaunchKernelGGL(k_fin, dim3(1), dim3(64), 0, stream, acc, out + (size_t)out_size - 1);
}

// Round 4
// 91.696 us; speedup vs baseline: 1.3138x; 1.3138x over previous
//
#include <hip/hip_runtime.h>
#include <stdint.h>

typedef short bf16x8 __attribute__((ext_vector_type(8)));
typedef float f32x4 __attribute__((ext_vector_type(4)));

__device__ __forceinline__ unsigned short f2bf(float f) {
  unsigned u = __float_as_uint(f);
  u += 0x7fffu + ((u >> 16) & 1u);   // RNE round to bf16
  return (unsigned short)(u >> 16);
}

// order-preserving float->u32 key (monotone increasing)
__device__ __forceinline__ unsigned fkey(float f) {
  unsigned u = __float_as_uint(f);
  return u ^ ((unsigned)(((int)u) >> 31) | 0x80000000u);
}

// ---------------- prep: emb fp32 -> bf16 (ws), half ||e||^2 ----------------
__global__ __launch_bounds__(256) void k_prep(const float* __restrict__ emb,
                                              unsigned short* __restrict__ embb,
                                              float* __restrict__ h2) {
  const int t = threadIdx.x;
  const int n = blockIdx.x * 8 + (t >> 5);
  const int c0 = (t & 31) * 8;
  const float* src = emb + (size_t)n * 256 + c0;
  float s = 0.f;
  union { bf16x8 v; unsigned short u[8]; } pk;
#pragma unroll
  for (int i = 0; i < 8; ++i) {
    float f = src[i];
    s += f * f;
    pk.u[i] = f2bf(f);
  }
  *(bf16x8*)(embb + (size_t)n * 256 + c0) = pk.v;
#pragma unroll
  for (int m = 1; m < 32; m <<= 1) s += __shfl_xor(s, m);
  if ((t & 31) == 0) h2[n] = 0.5f * s;
}

// ---------------- prez: z [B,C,H,W] fp32 -> zb [row=(b,hw)][c] bf16 + sum z^2
__global__ __launch_bounds__(256) void k_prez(const float* __restrict__ z,
                                              unsigned short* __restrict__ zb,
                                              float* __restrict__ acc) {
  __shared__ unsigned int lds[64 * 128];   // [hw][cpair ^ (hw&31)]
  __shared__ float rsum[4];
  const int t = threadIdx.x;
  const int b = blockIdx.x >> 4, hwg = blockIdx.x & 15;
  const int hw = t & 63, cq = t >> 6;
  const float* zp = z + (size_t)b * 262144 + hwg * 64 + hw;
  float ss = 0.f;
#pragma unroll
  for (int i = 0; i < 32; ++i) {
    const int c0 = cq * 64 + 2 * i;
    const float f0 = zp[(size_t)c0 * 1024];
    const float f1 = zp[(size_t)(c0 + 1) * 1024];
    ss += f0 * f0 + f1 * f1;
    const unsigned u = ((unsigned)f2bf(f1) << 16) | (unsigned)f2bf(f0);
    const int cp = cq * 32 + i;
    lds[hw * 128 + (cp ^ (hw & 31))] = u;
  }
#pragma unroll
  for (int m = 1; m < 64; m <<= 1) ss += __shfl_xor(ss, m);
  if ((t & 63) == 0) rsum[t >> 6] = ss;
  __syncthreads();
  if (t == 0) atomicAdd(acc, rsum[0] + rsum[1] + rsum[2] + rsum[3]);
  unsigned int* zbd = (unsigned int*)zb;
  const size_t tb = ((size_t)b * 1024 + hwg * 64) * 128;   // dword index
#pragma unroll
  for (int s = 0; s < 8; ++s) {
    const int r = s * 8 + (t >> 5);
    const int d0 = (t & 31) * 4;
    uint4 v;
    v.x = lds[r * 128 + ((d0 + 0) ^ (r & 31))];
    v.y = lds[r * 128 + ((d0 + 1) ^ (r & 31))];
    v.z = lds[r * 128 + ((d0 + 2) ^ (r & 31))];
    v.w = lds[r * 128 + ((d0 + 3) ^ (r & 31))];
    *(uint4*)(zbd + tb + (size_t)s * 1024 + (size_t)t * 4) = v;
  }
}

// ---------------- main: B(64 emb) resident in LDS, A streamed to regs ------
// grid: 1024 blocks = 16 ch x 64 rg; bid = ch*64 + rg -> same rg on same XCD.
// block: 4 waves x 128 rows = 512 rows x 64 emb. NO barriers in the loop.
__global__ __launch_bounds__(256, 3) void k_main(
    const unsigned short* __restrict__ zb, const unsigned short* __restrict__ embb,
    const float* __restrict__ h2, unsigned* __restrict__ best) {

  __shared__ __align__(16) unsigned short lB[64 * 256];   // 32 KB

  const int t = threadIdx.x;
  const int lane = t & 63;
  const int w = t >> 6;
  const int l15 = lane & 15;
  const int l4 = lane >> 4;
  const int rg = blockIdx.x & 63;
  const int ch = blockIdx.x >> 6;        // 0..15
  const int cb = ch * 64;

  // ---- load B chunk once: rows 0..63, swizzled 16B slots (linear LDS dest,
  // swizzle folded into per-lane global source address)
  {
    const unsigned short* base = embb + (size_t)cb * 256;
#pragma unroll
    for (int rd = 0; rd < 8; ++rd) {
      const int nl = rd * 8 + (t >> 5);
      const int p = t & 31;
      const int kc = p ^ (nl & 7);
      const unsigned short* g = base + (size_t)nl * 256 + kc * 8;
      char* l = (char*)lB + rd * 4096 + w * 1024;   // wave-uniform base
      __builtin_amdgcn_global_load_lds((const __attribute__((address_space(1))) void*)g,
                                       (__attribute__((address_space(3))) void*)l,
                                       16, 0, 0);
    }
  }
  // per-lane col constants
  float h[4];
  unsigned cio[4];
#pragma unroll
  for (int ni = 0; ni < 4; ++ni) {
    h[ni] = h2[cb + ni * 16 + l15];
    cio[ni] = (unsigned)(1023 - (cb + ni * 16 + l15));
  }
  asm volatile("s_waitcnt vmcnt(0)" ::: "memory");
  __syncthreads();   // the ONLY barrier

  const char* Az = (const char*)zb + ((size_t)(rg * 512 + w * 128) + l15) * 512 + l4 * 16;
  const int rowb0 = rg * 512 + w * 128;

#pragma unroll
  for (int g = 0; g < 2; ++g) {
    const char* ag = Az + (size_t)g * 64 * 512;
    f32x4 acc[4][4];
#pragma unroll
    for (int mi = 0; mi < 4; ++mi)
#pragma unroll
      for (int ni = 0; ni < 4; ++ni)
#pragma unroll
        for (int q = 0; q < 4; ++q) acc[mi][ni][q] = -h[ni];

#pragma unroll
    for (int kk = 0; kk < 8; ++kk) {
      bf16x8 a0 = *(const bf16x8*)(ag + 0 * 8192 + kk * 64);
      bf16x8 a1 = *(const bf16x8*)(ag + 1 * 8192 + kk * 64);
      bf16x8 a2 = *(const bf16x8*)(ag + 2 * 8192 + kk * 64);
      bf16x8 a3 = *(const bf16x8*)(ag + 3 * 8192 + kk * 64);
#pragma unroll
      for (int ni = 0; ni < 4; ++ni) {
        const int n = ni * 16 + l15;
        const int p = (kk * 4 + l4) ^ (n & 7);
        const bf16x8 bf = *(const bf16x8*)((const char*)lB + n * 512 + p * 16);
        acc[0][ni] = __builtin_amdgcn_mfma_f32_16x16x32_bf16(a0, bf, acc[0][ni], 0, 0, 0);
        acc[1][ni] = __builtin_amdgcn_mfma_f32_16x16x32_bf16(a1, bf, acc[1][ni], 0, 0, 0);
        acc[2][ni] = __builtin_amdgcn_mfma_f32_16x16x32_bf16(a2, bf, acc[2][ni], 0, 0, 0);
        acc[3][ni] = __builtin_amdgcn_mfma_f32_16x16x32_bf16(a3, bf, acc[3][ni], 0, 0, 0);
      }
    }

    // ---- fold: u32 key-max over ni, then over 16 lanes, then global atomic
#pragma unroll
    for (int mi = 0; mi < 4; ++mi)
#pragma unroll
      for (int j = 0; j < 4; ++j) {
        unsigned kbest = (fkey(acc[mi][0][j]) & 0xFFFFFC00u) | cio[0];
#pragma unroll
        for (int ni = 1; ni < 4; ++ni) {
          const unsigned kc = (fkey(acc[mi][ni][j]) & 0xFFFFFC00u) | cio[ni];
          kbest = kc > kbest ? kc : kbest;
        }
#pragma unroll
        for (int m = 1; m < 16; m <<= 1) {
          const unsigned ok = __shfl_xor((int)kbest, m);
          kbest = (unsigned)ok > kbest ? (unsigned)ok : kbest;
        }
        if (l15 == 0) atomicMax(&best[rowb0 + g * 64 + mi * 16 + l4 * 4 + j], kbest);
      }
  }
}

// ---------------- final: decode best, gather, transposed write, loss -------
__global__ __launch_bounds__(256) void k_final(const unsigned* __restrict__ best,
                                               const float* __restrict__ emb,
                                               float* __restrict__ out,
                                               float* __restrict__ acc) {
  __shared__ int sidx[64];
  __shared__ float lds[64 * 68];   // [c][hw], padded stride 68
  const int t = threadIdx.x;
  const int lane = t & 63;
  const int w = t >> 6;
  const int l15 = lane & 15;
  const int l4 = lane >> 4;
  const int b = blockIdx.x >> 4, hwg = blockIdx.x & 15;
  const int rowb = b * 1024 + hwg * 64;

  if (t < 64) {
    const unsigned p = best[rowb + t];
    sidx[t] = 1023 - (int)(p & 1023u);
    const unsigned k = p & 0xFFFFFC00u;
    const unsigned u = (k & 0x80000000u) ? (k & 0x7FFFFFFFu) : ~k;
    float s = __uint_as_float(u);
#pragma unroll
    for (int m = 1; m < 64; m <<= 1) s += __shfl_xor(s, m);
    if (t == 0) atomicAdd(acc, -2.f * s);
  }
  __syncthreads();

  const int hw = t & 63, cq = t >> 6;
  const float* ep = emb + (size_t)sidx[hw] * 256;
  float* ob = out + (size_t)b * 262144 + hwg * 64;
#pragma unroll
  for (int cc = 0; cc < 4; ++cc) {
    const int c0 = cc * 64 + cq * 16;
#pragma unroll
    for (int i = 0; i < 4; ++i) {
      const float4 v = *(const float4*)(ep + c0 + i * 4);
      lds[(cq * 16 + i * 4 + 0) * 68 + hw] = v.x;
      lds[(cq * 16 + i * 4 + 1) * 68 + hw] = v.y;
      lds[(cq * 16 + i * 4 + 2) * 68 + hw] = v.z;
      lds[(cq * 16 + i * 4 + 3) * 68 + hw] = v.w;
    }
    __syncthreads();
#pragma unroll
    for (int i = 0; i < 4; ++i) {
      const int c = w * 16 + i * 4 + l4;
      const float4 vv = *(const float4*)(&lds[c * 68 + l15 * 4]);
      *(float4*)(ob + (size_t)(cc * 64 + c) * 1024 + l15 * 4) = vv;
    }
    __syncthreads();
  }
}

// ---------------- finalize loss ----------------
__global__ void k_fin(const float* __restrict__ acc_g, float* __restrict__ lossp) {
  if (threadIdx.x == 0) lossp[0] = 1.25f * acc_g[0] * (1.0f / 8388608.0f);
}

extern "C" void kernel_launch(void* const* d_in, const int* in_sizes, int n_in,
                              void* d_out, int out_size, void* d_ws, size_t ws_size,
                              hipStream_t stream) {
  (void)in_sizes; (void)n_in; (void)ws_size;
  const float* z   = (const float*)d_in[0];
  const float* emb = (const float*)d_in[1];
  float* out = (float*)d_out;
  char* ws = (char*)d_ws;
  unsigned short* embb = (unsigned short*)ws;                  // 512 KB
  float* h2  = (float*)(ws + 524288);                          // 4 KB
  unsigned short* zb = (unsigned short*)(ws + (1 << 20));      // 16 MB
  unsigned* best = (unsigned*)(ws + (1 << 20) + 16777216);     // 128 KB
  float* acc = (float*)(ws + (1 << 20) + 16777216 + 131072);   // 4 B

  hipMemsetAsync(ws + (1 << 20) + 16777216, 0, 131072 + 16, stream);
  hipLaunchKernelGGL(k_prep, dim3(128), dim3(256), 0, stream, emb, embb, h2);
  hipLaunchKernelGGL(k_prez, dim3(512), dim3(256), 0, stream, z, zb, acc);
  hipLaunchKernelGGL(k_main, dim3(1024), dim3(256), 0, stream, zb, embb, h2, best);
  hipLaunchKernelGGL(k_final, dim3(512), dim3(256), 0, stream, best, emb, out, acc);
  hipLaunchKernelGGL(k_fin, dim3(1), dim3(64), 0, stream, acc, out + (size_t)out_size - 1);
}